// Round 3
// baseline (344.431 us; speedup 1.0000x reference)
//
#include <hip/hip_runtime.h>

// Submanifold sparse 3D conv, k=3, pad=1, no bias.
// Grid: 41 x 1024 x 1024, N=300000 active sites, C_in=32, C_out=64, fp32.
//
// R2 changes vs R1 (conv 241 us, FETCH 169 MB, latency-bound: VALU 23%, HBM 13%):
//  - Spatial counting sort (bucket = lin>>12): points processed in spatial
//    order -> hash-probe lines and coord reads become L2/L1-hot.
//    hist -> single-block scan -> scatter writes (orig,z,y,x) int4.
//  - LDS-staged feature gather: after ballot, valid pairs' 32-float feature
//    rows are loaded cooperatively (8 lanes x float4 per pair, 8 pairs/round,
//    one round typical since avg ~2.4 pairs/wave) -> one parallel memory
//    round instead of ~2.4 serial 700-cycle broadcast loads.
//  - FMA loop reads features from LDS (broadcast, conflict-free).

#define ZD 41
#define YD 1024
#define XD 1024

constexpr int CIN = 32;
constexpr int COUT = 64;
constexpr unsigned HASH_BITS = 20;               // 2^20 slots, load ~0.29
constexpr unsigned CAP = 1u << HASH_BITS;
constexpr unsigned GROUP_BITS = HASH_BITS - 3;   // octet groups
constexpr unsigned long long EMPTY = ~0ull;
constexpr int KEYSHIFT = 12;                     // 4096-voxel buckets (4 x-rows)
constexpr int NB = (ZD * YD * XD + (1 << KEYSHIFT) - 1) >> KEYSHIFT;  // 10496
constexpr int STAGE = 32;                        // staged pairs per wave (max 54)

__device__ __forceinline__ unsigned hash_slot(unsigned lin) {
    unsigned gh = ((lin >> 3) * 2654435761u) >> (32 - GROUP_BITS);
    return (gh << 3) | (lin & 7u);
}

__global__ void build_hash_hist_kernel(const int4* __restrict__ idx, int n,
                                       unsigned long long* __restrict__ table,
                                       unsigned* __restrict__ cnt, int do_hist) {
    int i = blockIdx.x * blockDim.x + threadIdx.x;
    if (i >= n) return;
    int4 c = idx[i];                             // (b, z, y, x)
    unsigned lin = (unsigned)(c.y * (YD * XD) + c.z * XD + c.w);
    unsigned long long packed = ((unsigned long long)(unsigned)i << 32) | (unsigned long long)lin;
    unsigned h = hash_slot(lin);
    while (atomicCAS(&table[h], EMPTY, packed) != EMPTY) {
        h = (h + 1) & (CAP - 1);                 // coords unique -> no dup check
    }
    if (do_hist) atomicAdd(&cnt[lin >> KEYSHIFT], 1u);
}

// Single-block exclusive scan over NB bucket counts (shfl wave-scan, few barriers).
__global__ __launch_bounds__(1024) void scan_kernel(const unsigned* __restrict__ cnt,
                                                    unsigned* __restrict__ off, int nb) {
    __shared__ unsigned wsum[16];
    __shared__ unsigned wbase[16];
    __shared__ unsigned carry_s;
    int tid = threadIdx.x, lane = tid & 63, wv = tid >> 6;
    if (tid == 0) carry_s = 0;
    __syncthreads();
    for (int base = 0; base < nb; base += 1024) {
        int i = base + tid;
        unsigned v = (i < nb) ? cnt[i] : 0;
        unsigned incl = v;
        for (int d = 1; d < 64; d <<= 1) {
            unsigned t = __shfl_up(incl, d, 64);
            if (lane >= d) incl += t;
        }
        if (lane == 63) wsum[wv] = incl;
        __syncthreads();
        if (wv == 0) {
            unsigned ws = (lane < 16) ? wsum[lane] : 0;
            unsigned wi = ws;
            for (int d = 1; d < 16; d <<= 1) {
                unsigned t = __shfl_up(wi, d, 64);
                if (lane >= d) wi += t;
            }
            if (lane < 16) wbase[lane] = wi - ws;
        }
        __syncthreads();
        unsigned carry = carry_s;
        if (i < nb) off[i] = carry + wbase[wv] + incl - v;
        __syncthreads();
        if (tid == 1023) carry_s = carry + wbase[15] + wsum[15];
        __syncthreads();
    }
}

__global__ void scatter_kernel(const int4* __restrict__ idx, int n,
                               unsigned* __restrict__ off, int4* __restrict__ sorted) {
    int i = blockIdx.x * blockDim.x + threadIdx.x;
    if (i >= n) return;
    int4 c = idx[i];
    unsigned lin = (unsigned)(c.y * (YD * XD) + c.z * XD + c.w);
    unsigned pos = atomicAdd(&off[lin >> KEYSHIFT], 1u);
    sorted[pos] = make_int4(i, c.y, c.z, c.w);   // (orig, z, y, x)
}

__device__ __forceinline__ int lookup(const unsigned long long* __restrict__ table,
                                      unsigned lin) {
    unsigned h = hash_slot(lin);
    while (true) {
        unsigned long long s = table[h];
        if (s == EMPTY) return -1;
        if ((unsigned)s == lin) return (int)(s >> 32);
        h = (h + 1) & (CAP - 1);
    }
}

__global__ __launch_bounds__(256) void subm_conv_kernel(
    const float* __restrict__ feat, const int4* __restrict__ pts,
    const float* __restrict__ weight, const unsigned long long* __restrict__ table,
    float* __restrict__ out, int n, int sorted_flag) {
    __shared__ float lds_feat[4][STAGE * 32];    // 16 KB: staged feature rows
    __shared__ unsigned lds_list[4][64];         // (ni<<6)|(half<<5)|k per pair

    int wid = threadIdx.x >> 6;
    int lane = threadIdx.x & 63;
    int wave = blockIdx.x * 4 + wid;
    int p0 = wave * 2, p1 = p0 + 1;
    if (p0 >= n) return;
    bool has_b = (p1 < n);

    int half = lane >> 5;                        // 0 = point A, 1 = point B
    int off  = lane & 31;
    int pi = (half && has_b) ? p1 : p0;
    int4 c = pts[pi];
    int orig = sorted_flag ? c.x : pi;           // feature-row / output index

    int nidx = -1;
    if (off < 27 && (half == 0 || has_b)) {
        if (off == 13) {
            nidx = orig;                         // center tap: the point itself
        } else {
            int dz = off / 9 - 1;
            int dy = (off / 3) % 3 - 1;
            int dx = off % 3 - 1;
            int nz = c.y + dz, ny = c.z + dy, nx = c.w + dx;
            if ((unsigned)nz < (unsigned)ZD && (unsigned)ny < (unsigned)YD &&
                (unsigned)nx < (unsigned)XD) {
                nidx = lookup(table, (unsigned)(nz * (YD * XD) + ny * XD + nx));
            }
        }
    }

    unsigned long long mask = __ballot(nidx >= 0);
    int cnt = __popcll(mask);

    if (nidx >= 0) {
        int r = __popcll(mask & ((1ull << lane) - 1ull));
        lds_list[wid][r] = ((unsigned)nidx << 6) | ((unsigned)half << 5) | (unsigned)off;
    }
    __asm__ __volatile__("s_waitcnt lgkmcnt(0)" ::: "memory");

    // Cooperative stage: pair j's 32-float row loaded by 8 lanes (float4 each).
    int scnt = cnt < STAGE ? cnt : STAGE;
    int ps = lane >> 3, fl = lane & 7;
    for (int base = 0; base < scnt; base += 8) {
        int j = base + ps;
        if (j < scnt) {
            unsigned e = lds_list[wid][j];
            int ni = (int)(e >> 6);
            float4 f = *(const float4*)(feat + (size_t)ni * CIN + fl * 4);
            *(float4*)&lds_feat[wid][j * 32 + fl * 4] = f;
        }
    }
    __asm__ __volatile__("s_waitcnt vmcnt(0) lgkmcnt(0)" ::: "memory");

    float a0 = 0.f, a1 = 0.f, a2 = 0.f, a3 = 0.f;
    float b0 = 0.f, b1 = 0.f, b2 = 0.f, b3 = 0.f;

    for (int j = 0; j < scnt; ++j) {
        unsigned e = lds_list[wid][j];           // broadcast read (uniform)
        int k  = (int)(e & 31u);
        int hb = (int)((e >> 5) & 1u);
        const float4* lf = (const float4*)&lds_feat[wid][j * 32];
        const float* wk = weight + k * (CIN * COUT);
        if (hb == 0) {                           // wave-uniform branch
#pragma unroll
            for (int q = 0; q < 8; ++q) {
                float4 f = lf[q];
                a0 = fmaf(f.x, wk[(4 * q + 0) * COUT + lane], a0);
                a1 = fmaf(f.y, wk[(4 * q + 1) * COUT + lane], a1);
                a2 = fmaf(f.z, wk[(4 * q + 2) * COUT + lane], a2);
                a3 = fmaf(f.w, wk[(4 * q + 3) * COUT + lane], a3);
            }
        } else {
#pragma unroll
            for (int q = 0; q < 8; ++q) {
                float4 f = lf[q];
                b0 = fmaf(f.x, wk[(4 * q + 0) * COUT + lane], b0);
                b1 = fmaf(f.y, wk[(4 * q + 1) * COUT + lane], b1);
                b2 = fmaf(f.z, wk[(4 * q + 2) * COUT + lane], b2);
                b3 = fmaf(f.w, wk[(4 * q + 3) * COUT + lane], b3);
            }
        }
    }

    if (__builtin_expect(cnt > STAGE, 0)) {      // rare tail: direct broadcast path
        unsigned long long m = mask;
        for (int t = 0; t < STAGE; ++t) m &= m - 1;
        while (m) {
            int src = __ffsll((unsigned long long)m) - 1;
            m &= m - 1;
            int ni = __shfl(nidx, src);
            int k = src & 31, hb = src >> 5;
            const float4* f4 = (const float4*)(feat + (size_t)ni * CIN);
            const float* wk = weight + k * (CIN * COUT);
            if (hb == 0) {
#pragma unroll
                for (int q = 0; q < 8; ++q) {
                    float4 f = f4[q];
                    a0 = fmaf(f.x, wk[(4 * q + 0) * COUT + lane], a0);
                    a1 = fmaf(f.y, wk[(4 * q + 1) * COUT + lane], a1);
                    a2 = fmaf(f.z, wk[(4 * q + 2) * COUT + lane], a2);
                    a3 = fmaf(f.w, wk[(4 * q + 3) * COUT + lane], a3);
                }
            } else {
#pragma unroll
                for (int q = 0; q < 8; ++q) {
                    float4 f = f4[q];
                    b0 = fmaf(f.x, wk[(4 * q + 0) * COUT + lane], b0);
                    b1 = fmaf(f.y, wk[(4 * q + 1) * COUT + lane], b1);
                    b2 = fmaf(f.z, wk[(4 * q + 2) * COUT + lane], b2);
                    b3 = fmaf(f.w, wk[(4 * q + 3) * COUT + lane], b3);
                }
            }
        }
    }

    int origA = __shfl(orig, 0);
    int origB = __shfl(orig, 32);
    out[(size_t)origA * COUT + lane] = (a0 + a1) + (a2 + a3);
    if (has_b) out[(size_t)origB * COUT + lane] = (b0 + b1) + (b2 + b3);
}

extern "C" void kernel_launch(void* const* d_in, const int* in_sizes, int n_in,
                              void* d_out, int out_size, void* d_ws, size_t ws_size,
                              hipStream_t stream) {
    const float* feat   = (const float*)d_in[0];   // [N, 32]
    const int4*  idx    = (const int4*)d_in[1];    // [N, 4] int32 (b,z,y,x)
    const float* weight = (const float*)d_in[2];   // [27, 32, 64]
    float* out = (float*)d_out;                    // [N, 64]
    int n = in_sizes[0] / CIN;

    unsigned char* base = (unsigned char*)d_ws;
    unsigned long long* table = (unsigned long long*)base;             // 8 MB
    unsigned* cntp = (unsigned*)(base + (size_t)CAP * 8);              // NB u32
    unsigned* offp = cntp + NB;                                        // NB u32
    int4* sorted   = (int4*)(offp + NB);                               // N int4

    size_t need = (size_t)CAP * 8 + (size_t)NB * 8 + (size_t)n * 16;
    int use_sort = (ws_size >= need) ? 1 : 0;      // deterministic per env

    hipMemsetAsync(table, 0xFF, (size_t)CAP * sizeof(unsigned long long), stream);
    if (use_sort) hipMemsetAsync(cntp, 0, (size_t)NB * 4, stream);

    int bblocks = (n + 255) / 256;
    build_hash_hist_kernel<<<bblocks, 256, 0, stream>>>(idx, n, table, cntp, use_sort);

    const int4* pts = idx;
    if (use_sort) {
        scan_kernel<<<1, 1024, 0, stream>>>(cntp, offp, NB);
        scatter_kernel<<<bblocks, 256, 0, stream>>>(idx, n, offp, sorted);
        pts = sorted;
    }

    int waves = (n + 1) / 2;                       // 2 points per wave
    int cblocks = (waves + 3) / 4;                 // 4 waves per block
    subm_conv_kernel<<<cblocks, 256, 0, stream>>>(feat, pts, weight, table, out, n, use_sort);
}

// Round 4
// 288.781 us; speedup vs baseline: 1.1927x; 1.1927x over previous
//
#include <hip/hip_runtime.h>

// Submanifold sparse 3D conv, k=3, pad=1, no bias.
// Grid: 41 x 1024 x 1024, N=300000 active sites, C_in=32, C_out=64, fp32.
//
// R3 changes vs R2 (conv 200 us, FETCH 167 MB, latency-bound; sort = no gain):
//  - DROP the spatial sort (hist/scan/scatter): FETCH was unchanged by it,
//    probe lines are ~unique per point (no reuse to exploit), cost ~45 us.
//  - Coarse octet-occupancy bitmap (1 bit / 8 voxels = 656 KB, L2-resident):
//    probe bitmap first; only ~5.5% of octets occupied -> hash lookups drop
//    26/pt -> ~1.4/pt. Cuts ~115 MB probe HBM traffic to ~30 MB and turns
//    the common probe path into an L2 hit.
//  - Center tap (always valid, 85% of pairs): its feature row is loaded at
//    kernel entry (coalesced, independent) IN PARALLEL with the probe round,
//    removing one serial HBM round from the dominant path.
//  - Nontemporal out stores (75 MB write-once; keep bitmap/weights hot in L2).

#define ZD 41
#define YD 1024
#define XD 1024

constexpr int CIN = 32;
constexpr int COUT = 64;
constexpr unsigned HASH_BITS = 20;               // 2^20 slots, load ~0.29
constexpr unsigned CAP = 1u << HASH_BITS;
constexpr unsigned GROUP_BITS = HASH_BITS - 3;   // octet groups
constexpr unsigned long long EMPTY = ~0ull;
constexpr unsigned NVOX = ZD * YD * XD;          // 42,991,616
constexpr unsigned NOCT = NVOX / 8;              // 5,373,952 octets
constexpr unsigned BMWORDS = (NOCT + 31) / 32;   // 167,936 u32 = 656 KB
constexpr int STAGE = 32;                        // feature slots per wave (2 center + 30)

__device__ __forceinline__ unsigned hash_slot(unsigned lin) {
    unsigned gh = ((lin >> 3) * 2654435761u) >> (32 - GROUP_BITS);
    return (gh << 3) | (lin & 7u);
}

__global__ void build_hash_kernel(const int4* __restrict__ idx, int n,
                                  unsigned long long* __restrict__ table,
                                  unsigned* __restrict__ bitmap) {
    int i = blockIdx.x * blockDim.x + threadIdx.x;
    if (i >= n) return;
    int4 c = idx[i];                             // (b, z, y, x)
    unsigned lin = (unsigned)(c.y * (YD * XD) + c.z * XD + c.w);
    unsigned g = lin >> 3;
    atomicOr(&bitmap[g >> 5], 1u << (g & 31u));
    unsigned long long packed = ((unsigned long long)(unsigned)i << 32) | (unsigned long long)lin;
    unsigned h = hash_slot(lin);
    while (atomicCAS(&table[h], EMPTY, packed) != EMPTY) {
        h = (h + 1) & (CAP - 1);                 // coords unique -> no dup check
    }
}

__device__ __forceinline__ int lookup(const unsigned long long* __restrict__ table,
                                      unsigned lin) {
    unsigned h = hash_slot(lin);
    while (true) {
        unsigned long long s = table[h];
        if (s == EMPTY) return -1;
        if ((unsigned)s == lin) return (int)(s >> 32);
        h = (h + 1) & (CAP - 1);
    }
}

__global__ __launch_bounds__(256) void subm_conv_kernel(
    const float* __restrict__ feat, const int4* __restrict__ idx,
    const float* __restrict__ weight, const unsigned long long* __restrict__ table,
    const unsigned* __restrict__ bitmap, float* __restrict__ out, int n) {
    __shared__ float lds_feat[4][STAGE * 32];    // 16 KB: feature rows
    __shared__ unsigned lds_list[4][64];         // (ni<<6)|(half<<5)|k

    int wid = threadIdx.x >> 6;
    int lane = threadIdx.x & 63;
    int wave = blockIdx.x * 4 + wid;
    int p0 = wave * 2, p1 = p0 + 1;
    if (p0 >= n) return;
    bool has_b = (p1 < n);

    // --- center-tap feature rows: independent, issue before the probe chain.
    // lanes 0..7 load point A's 32 floats (float4 each), lanes 8..15 point B's.
    float4 cf;
    if (lane < 16) {
        int crow = (has_b && lane >= 8) ? p1 : p0;
        cf = *(const float4*)(feat + (size_t)crow * CIN + (size_t)(lane & 7) * 4);
    }

    // --- neighbor probes for the 26 non-center offsets.
    int half = lane >> 5;                        // 0 = point A, 1 = point B
    int po   = lane & 31;
    int p = (half && has_b) ? p1 : p0;
    int4 c = idx[p];

    int nidx = -1;
    if (po < 26 && (half == 0 || has_b)) {
        int off = po + (po >= 13);               // skip center (13)
        int dz = off / 9 - 1;
        int dy = (off / 3) % 3 - 1;
        int dx = off % 3 - 1;
        int nz = c.y + dz, ny = c.z + dy, nx = c.w + dx;
        if ((unsigned)nz < (unsigned)ZD && (unsigned)ny < (unsigned)YD &&
            (unsigned)nx < (unsigned)XD) {
            unsigned nlin = (unsigned)(nz * (YD * XD) + ny * XD + nx);
            unsigned g = nlin >> 3;
            if ((bitmap[g >> 5] >> (g & 31u)) & 1u) {   // L2-hot prefilter
                nidx = lookup(table, nlin);
            }
        }
    }

    unsigned long long mask = __ballot(nidx >= 0);
    int cnt = __popcll(mask);

    // list entries: slots 0,1 = center taps; 2.. = valid neighbors.
    if (lane == 0) lds_list[wid][0] = ((unsigned)p0 << 6) | 13u;
    if (lane == 1 && has_b) lds_list[wid][1] = ((unsigned)p1 << 6) | (1u << 5) | 13u;
    if (nidx >= 0) {
        int r = __popcll(mask & ((1ull << lane) - 1ull));
        if (r < STAGE - 2) {
            lds_list[wid][2 + r] =
                ((unsigned)nidx << 6) | ((unsigned)half << 5) | (unsigned)(po + (po >= 13));
        }
    }
    if (lane < 16) {                             // center rows -> slots 0,1
        *(float4*)&lds_feat[wid][(lane >> 3) * 32 + (lane & 7) * 4] = cf;
    }
    __asm__ __volatile__("s_waitcnt lgkmcnt(0)" ::: "memory");

    // --- cooperative stage of valid-neighbor rows into slots 2..
    int scnt = cnt < (STAGE - 2) ? cnt : (STAGE - 2);
    int ps = lane >> 3, fl = lane & 7;
    for (int base = 0; base < scnt; base += 8) {
        int j = base + ps;
        if (j < scnt) {
            unsigned e = lds_list[wid][2 + j];
            int ni = (int)(e >> 6);
            float4 f = *(const float4*)(feat + (size_t)ni * CIN + (size_t)fl * 4);
            *(float4*)&lds_feat[wid][(2 + j) * 32 + fl * 4] = f;
        }
    }
    __asm__ __volatile__("s_waitcnt vmcnt(0) lgkmcnt(0)" ::: "memory");

    float a0 = 0.f, a1 = 0.f, a2 = 0.f, a3 = 0.f;
    float b0 = 0.f, b1 = 0.f, b2 = 0.f, b3 = 0.f;

    int total = 2 + scnt;
    for (int j = 0; j < total; ++j) {
        if (j == 1 && !has_b) continue;          // wave-uniform
        unsigned e = lds_list[wid][j];           // broadcast read
        int k  = (int)(e & 31u);
        int hb = (int)((e >> 5) & 1u);
        const float4* lf = (const float4*)&lds_feat[wid][j * 32];
        const float* wk = weight + k * (CIN * COUT);
        if (hb == 0) {                           // wave-uniform branch
#pragma unroll
            for (int q = 0; q < 8; ++q) {
                float4 f = lf[q];
                a0 = fmaf(f.x, wk[(4 * q + 0) * COUT + lane], a0);
                a1 = fmaf(f.y, wk[(4 * q + 1) * COUT + lane], a1);
                a2 = fmaf(f.z, wk[(4 * q + 2) * COUT + lane], a2);
                a3 = fmaf(f.w, wk[(4 * q + 3) * COUT + lane], a3);
            }
        } else {
#pragma unroll
            for (int q = 0; q < 8; ++q) {
                float4 f = lf[q];
                b0 = fmaf(f.x, wk[(4 * q + 0) * COUT + lane], b0);
                b1 = fmaf(f.y, wk[(4 * q + 1) * COUT + lane], b1);
                b2 = fmaf(f.z, wk[(4 * q + 2) * COUT + lane], b2);
                b3 = fmaf(f.w, wk[(4 * q + 3) * COUT + lane], b3);
            }
        }
    }

    if (__builtin_expect(cnt > STAGE - 2, 0)) {  // rare tail: direct broadcast path
        unsigned long long m = mask;
        for (int t = 0; t < STAGE - 2; ++t) m &= m - 1;
        while (m) {
            int src = __ffsll((unsigned long long)m) - 1;
            m &= m - 1;
            int ni = __shfl(nidx, src);
            int sp = src & 31;
            int k = sp + (sp >= 13);
            int hb = src >> 5;
            const float4* f4 = (const float4*)(feat + (size_t)ni * CIN);
            const float* wk = weight + k * (CIN * COUT);
            if (hb == 0) {
#pragma unroll
                for (int q = 0; q < 8; ++q) {
                    float4 f = f4[q];
                    a0 = fmaf(f.x, wk[(4 * q + 0) * COUT + lane], a0);
                    a1 = fmaf(f.y, wk[(4 * q + 1) * COUT + lane], a1);
                    a2 = fmaf(f.z, wk[(4 * q + 2) * COUT + lane], a2);
                    a3 = fmaf(f.w, wk[(4 * q + 3) * COUT + lane], a3);
                }
            } else {
#pragma unroll
                for (int q = 0; q < 8; ++q) {
                    float4 f = f4[q];
                    b0 = fmaf(f.x, wk[(4 * q + 0) * COUT + lane], b0);
                    b1 = fmaf(f.y, wk[(4 * q + 1) * COUT + lane], b1);
                    b2 = fmaf(f.z, wk[(4 * q + 2) * COUT + lane], b2);
                    b3 = fmaf(f.w, wk[(4 * q + 3) * COUT + lane], b3);
                }
            }
        }
    }

    __builtin_nontemporal_store((a0 + a1) + (a2 + a3), &out[(size_t)p0 * COUT + lane]);
    if (has_b) {
        __builtin_nontemporal_store((b0 + b1) + (b2 + b3), &out[(size_t)p1 * COUT + lane]);
    }
}

extern "C" void kernel_launch(void* const* d_in, const int* in_sizes, int n_in,
                              void* d_out, int out_size, void* d_ws, size_t ws_size,
                              hipStream_t stream) {
    const float* feat   = (const float*)d_in[0];   // [N, 32]
    const int4*  idx    = (const int4*)d_in[1];    // [N, 4] int32 (b,z,y,x)
    const float* weight = (const float*)d_in[2];   // [27, 32, 64]
    float* out = (float*)d_out;                    // [N, 64]
    int n = in_sizes[0] / CIN;

    unsigned char* base = (unsigned char*)d_ws;
    unsigned long long* table = (unsigned long long*)base;              // 8 MB
    unsigned* bitmap = (unsigned*)(base + (size_t)CAP * 8);             // 656 KB

    hipMemsetAsync(table, 0xFF, (size_t)CAP * sizeof(unsigned long long), stream);
    hipMemsetAsync(bitmap, 0, (size_t)BMWORDS * 4, stream);

    int bblocks = (n + 255) / 256;
    build_hash_kernel<<<bblocks, 256, 0, stream>>>(idx, n, table, bitmap);

    int waves = (n + 1) / 2;                       // 2 points per wave
    int cblocks = (waves + 3) / 4;                 // 4 waves per block
    subm_conv_kernel<<<cblocks, 256, 0, stream>>>(feat, idx, weight, table, bitmap, out, n);
}

// Round 5
// 240.222 us; speedup vs baseline: 1.4338x; 1.2021x over previous
//
#include <hip/hip_runtime.h>

// Submanifold sparse 3D conv, k=3, pad=1, no bias.
// Grid: 41 x 1024 x 1024, N=300000 active sites, C_in=32, C_out=64, fp32.
//
// R4 restructure vs R3 (conv 172 us, latency-bound: VALU 35%, HBM 9.5%):
//  - 16 points per wave (was 2): 18.75k waves instead of 150k; per-wave VALU
//    ~2kcyc so resident waves have real work to hide probe latency under.
//  - Center tap (85% of FLOPs) as register-weight dense GEMM: lane keeps all
//    32 W13 values in VGPRs (one coalesced load set per wave) -> zero weight
//    traffic in the dominant path; feature rows staged coalesced into LDS and
//    consumed via ds_read_b128.
//  - Per-wave LDS accumulators accum[16][64]: center writes init, neighbor
//    hits do in-order LDS RMW (no atomics, no dynamic reg indexing), one
//    coalesced nontemporal store pass at the end.
//  - Probe order: bitmap words for all 7 offset-rounds issued BEFORE the
//    center FMA; hash lookups (~0.35/lane) resolved after it.
//  - One merged 0xFF memset (table + inverted bitmap): 3 dispatches total.

#define ZD 41
#define YD 1024
#define XD 1024

constexpr int CIN = 32;
constexpr int COUT = 64;
constexpr unsigned HASH_BITS = 20;               // 2^20 slots, load ~0.29
constexpr unsigned CAP = 1u << HASH_BITS;
constexpr unsigned GROUP_BITS = HASH_BITS - 3;   // octet groups
constexpr unsigned long long EMPTY = ~0ull;
constexpr unsigned NVOX = ZD * YD * XD;          // 42,991,616
constexpr unsigned NOCT = NVOX / 8;              // 5,373,952 octets
constexpr unsigned BMWORDS = (NOCT + 31) / 32;   // 167,936 u32 (bit=1: EMPTY)
constexpr int PPW = 16;                          // points per wave
constexpr int NSLOT = 24;                        // 16 center rows + 8 hit rows
constexpr int LCAP = 64;                         // hit-list capacity per wave

__device__ __forceinline__ unsigned hash_slot(unsigned lin) {
    unsigned gh = ((lin >> 3) * 2654435761u) >> (32 - GROUP_BITS);
    return (gh << 3) | (lin & 7u);
}

__global__ void build_hash_kernel(const int4* __restrict__ idx, int n,
                                  unsigned long long* __restrict__ table,
                                  unsigned* __restrict__ bitmap) {
    int i = blockIdx.x * blockDim.x + threadIdx.x;
    if (i >= n) return;
    int4 c = idx[i];                             // (b, z, y, x)
    unsigned lin = (unsigned)(c.y * (YD * XD) + c.z * XD + c.w);
    unsigned g = lin >> 3;
    atomicAnd(&bitmap[g >> 5], ~(1u << (g & 31u)));   // clear bit = occupied
    unsigned long long packed = ((unsigned long long)(unsigned)i << 32) | (unsigned long long)lin;
    unsigned h = hash_slot(lin);
    while (atomicCAS(&table[h], EMPTY, packed) != EMPTY) {
        h = (h + 1) & (CAP - 1);                 // coords unique -> no dup check
    }
}

__device__ __forceinline__ int lookup(const unsigned long long* __restrict__ table,
                                      unsigned lin) {
    unsigned h = hash_slot(lin);
    while (true) {
        unsigned long long s = table[h];
        if (s == EMPTY) return -1;
        if ((unsigned)s == lin) return (int)(s >> 32);
        h = (h + 1) & (CAP - 1);
    }
}

__global__ __launch_bounds__(256) void subm_conv_kernel(
    const float* __restrict__ feat, const int4* __restrict__ idx,
    const float* __restrict__ weight, const unsigned long long* __restrict__ table,
    const unsigned* __restrict__ bitmap, float* __restrict__ out, int n) {
    __shared__ float rows[4][NSLOT][CIN];        // 12 KB
    __shared__ float accum[4][PPW * COUT];       // 16 KB
    __shared__ unsigned hlist[4][LCAP];          // 1 KB

    int wid = threadIdx.x >> 6;
    int lane = threadIdx.x & 63;
    int p0 = (blockIdx.x * 4 + wid) * PPW;
    if (p0 >= n) return;
    int np = min(PPW, n - p0);

    // --- 1) center feature rows -> LDS, coalesced (independent of everything)
#pragma unroll
    for (int r = 0; r < 2; ++r) {
        int j = r * 64 + lane;
        int row = j >> 3, seg = j & 7;
        if (row < np) {
            float4 f = *(const float4*)(feat + (size_t)(p0 + row) * CIN + seg * 4);
            *(float4*)&rows[wid][row][seg * 4] = f;
        }
    }

    // --- 2) W13 column into registers (32 coalesced loads, L2-hot)
    const float* w13p = weight + 13 * (CIN * COUT) + lane;
    float w13[CIN];
#pragma unroll
    for (int ci = 0; ci < CIN; ++ci) w13[ci] = w13p[ci * COUT];

    // --- 3) coords: 4 lanes per point (merged 16B broadcast loads)
    int pt = lane >> 2;
    int4 c = idx[p0 + (pt < np ? pt : 0)];

    // --- 4) bitmap words for all 7 probe rounds (issued before dense work)
    unsigned nlin_t[7];
    unsigned bmw[7];
    bool try_t[7];
#pragma unroll
    for (int t = 0; t < 7; ++t) {
        int off = (lane & 3) + 4 * t;
        int k = off + (off >= 13);
        bool ok = (off < 26) && (pt < np);
        int dz = k / 9 - 1, dy = (k / 3) % 3 - 1, dx = k % 3 - 1;
        int nz = c.y + dz, ny = c.z + dy, nx = c.w + dx;
        ok = ok && (unsigned)nz < (unsigned)ZD && (unsigned)ny < (unsigned)YD &&
             (unsigned)nx < (unsigned)XD;
        unsigned nlin = ok ? (unsigned)(nz * (YD * XD) + ny * XD + nx) : 0u;
        nlin_t[t] = nlin;
        try_t[t] = ok;
        bmw[t] = ok ? bitmap[(nlin >> 3) >> 5] : ~0u;   // bit=1 means empty
    }

    // --- 5) center GEMM: rows from LDS (b128 broadcast), weights in regs
    for (int g = 0; g < np; ++g) {
        const float4* fr = (const float4*)rows[wid][g];
        float s0 = 0.f, s1 = 0.f, s2 = 0.f, s3 = 0.f;
#pragma unroll
        for (int q = 0; q < 8; ++q) {
            float4 f = fr[q];
            s0 = fmaf(f.x, w13[4 * q + 0], s0);
            s1 = fmaf(f.y, w13[4 * q + 1], s1);
            s2 = fmaf(f.z, w13[4 * q + 2], s2);
            s3 = fmaf(f.w, w13[4 * q + 3], s3);
        }
        accum[wid][g * COUT + lane] = (s0 + s1) + (s2 + s3);
    }

    // --- 6) resolve probes (bitmap words are long since arrived)
    int nid[7];
#pragma unroll
    for (int t = 0; t < 7; ++t) {
        int ni = -1;
        if (try_t[t]) {
            unsigned nlin = nlin_t[t];
            if (!((bmw[t] >> ((nlin >> 3) & 31u)) & 1u)) {   // occupied octet
                ni = lookup(table, nlin);
            }
        }
        nid[t] = ni;
    }

    // --- 7) record hits into per-wave list
    int base = 0;
    unsigned ovbits = 0;
#pragma unroll
    for (int t = 0; t < 7; ++t) {
        unsigned long long m = __ballot(nid[t] >= 0);
        if (nid[t] >= 0) {
            int r = base + __popcll(m & ((1ull << lane) - 1ull));
            int off = (lane & 3) + 4 * t;
            int k = off + (off >= 13);
            if (r < LCAP) {
                hlist[wid][r] = ((unsigned)nid[t] << 9) | ((unsigned)pt << 5) | (unsigned)k;
            } else {
                ovbits |= 1u << t;
            }
        }
        base += __popcll(m);
    }
    int hits = base < LCAP ? base : LCAP;
    __asm__ __volatile__("s_waitcnt lgkmcnt(0)" ::: "memory");

    // --- 8) hit rounds: stage up to 8 rows (one full-wave round) then FMA
    for (int done = 0; done < hits; done += 8) {
        int cnt = min(8, hits - done);
        int j = lane >> 3, seg = lane & 7;
        if (j < cnt) {
            unsigned e = hlist[wid][done + j];
            int ni = (int)(e >> 9);
            float4 f = *(const float4*)(feat + (size_t)ni * CIN + seg * 4);
            *(float4*)&rows[wid][PPW + j][seg * 4] = f;
        }
        __asm__ __volatile__("s_waitcnt vmcnt(0) lgkmcnt(0)" ::: "memory");
        for (int j2 = 0; j2 < cnt; ++j2) {
            unsigned e = hlist[wid][done + j2];          // LDS broadcast
            int pt2 = (int)((e >> 5) & 15u);
            int k = (int)(e & 31u);
            const float* wk = weight + k * (CIN * COUT) + lane;
            const float4* fr = (const float4*)rows[wid][PPW + j2];
            float s0 = 0.f, s1 = 0.f, s2 = 0.f, s3 = 0.f;
#pragma unroll
            for (int q = 0; q < 8; ++q) {
                float4 f = fr[q];
                s0 = fmaf(f.x, wk[(4 * q + 0) * COUT], s0);
                s1 = fmaf(f.y, wk[(4 * q + 1) * COUT], s1);
                s2 = fmaf(f.z, wk[(4 * q + 2) * COUT], s2);
                s3 = fmaf(f.w, wk[(4 * q + 3) * COUT], s3);
            }
            accum[wid][pt2 * COUT + lane] += (s0 + s1) + (s2 + s3);
        }
        __asm__ __volatile__("s_waitcnt lgkmcnt(0)" ::: "memory");
    }

    // --- 9) rare overflow (hits beyond LCAP): direct broadcast path
    if (__builtin_expect(base > LCAP, 0)) {
#pragma unroll
        for (int t = 0; t < 7; ++t) {
            unsigned long long m = __ballot((ovbits >> t) & 1u);
            while (m) {
                int src = __ffsll((unsigned long long)m) - 1;
                m &= m - 1;
                int ni = __shfl(nid[t], src);
                int pt2 = src >> 2;
                int off = (src & 3) + 4 * t;
                int k = off + (off >= 13);
                const float4* fr = (const float4*)(feat + (size_t)ni * CIN);
                const float* wk = weight + k * (CIN * COUT) + lane;
                float s0 = 0.f, s1 = 0.f, s2 = 0.f, s3 = 0.f;
#pragma unroll
                for (int q = 0; q < 8; ++q) {
                    float4 f = fr[q];
                    s0 = fmaf(f.x, wk[(4 * q + 0) * COUT], s0);
                    s1 = fmaf(f.y, wk[(4 * q + 1) * COUT], s1);
                    s2 = fmaf(f.z, wk[(4 * q + 2) * COUT], s2);
                    s3 = fmaf(f.w, wk[(4 * q + 3) * COUT], s3);
                }
                accum[wid][pt2 * COUT + lane] += (s0 + s1) + (s2 + s3);
            }
        }
        __asm__ __volatile__("s_waitcnt lgkmcnt(0)" ::: "memory");
    }

    // --- 10) coalesced store pass
    for (int g = 0; g < np; ++g) {
        __builtin_nontemporal_store(accum[wid][g * COUT + lane],
                                    &out[(size_t)(p0 + g) * COUT + lane]);
    }
}

extern "C" void kernel_launch(void* const* d_in, const int* in_sizes, int n_in,
                              void* d_out, int out_size, void* d_ws, size_t ws_size,
                              hipStream_t stream) {
    const float* feat   = (const float*)d_in[0];   // [N, 32]
    const int4*  idx    = (const int4*)d_in[1];    // [N, 4] int32 (b,z,y,x)
    const float* weight = (const float*)d_in[2];   // [27, 32, 64]
    float* out = (float*)d_out;                    // [N, 64]
    int n = in_sizes[0] / CIN;

    unsigned char* base = (unsigned char*)d_ws;
    unsigned long long* table = (unsigned long long*)base;              // 8 MB
    unsigned* bitmap = (unsigned*)(base + (size_t)CAP * 8);             // 656 KB

    // One memset covers table (0xFF = EMPTY) and bitmap (0xFF = all-empty).
    hipMemsetAsync(table, 0xFF, (size_t)CAP * 8 + (size_t)BMWORDS * 4, stream);

    int bblocks = (n + 255) / 256;
    build_hash_kernel<<<bblocks, 256, 0, stream>>>(idx, n, table, bitmap);

    int ppb = 4 * PPW;                             // 64 points per block
    int cblocks = (n + ppb - 1) / ppb;
    subm_conv_kernel<<<cblocks, 256, 0, stream>>>(feat, idx, weight, table, bitmap, out, n);
}

// Round 7
// 187.194 us; speedup vs baseline: 1.8400x; 1.2833x over previous
//
#include <hip/hip_runtime.h>
#include <hip/hip_fp16.h>

// Submanifold sparse 3D conv, k=3, pad=1, no bias.
// Grid: 41 x 1024 x 1024, N=300000 active sites, C_in=32, C_out=64, fp32 I/O.
//
// R6 = R5 with the cvt_pkrtz type fix (__fp16 vs _Float16 vector types).
// R5 vs R4 (conv 119 us, LDS-pipe-bound: ~304 ds_read_b128/wave ~ 4.15kcyc):
//  - Center tap via MFMA f16: 4 x v_mfma_f32_16x16x32_f16 per 16-point wave
//    (A gathered per-lane from global, B from pre-packed f16 weights) replaces
//    128 LDS broadcast reads + 1kcyc VALU. C scattered into LDS accum.
//  - Hits in packed f16: weights pre-packed to [27][4][64] uint4 (8 f16) ->
//    4 coalesced loads/hit (was 32); rows staged as f16 -> 4 ds_read_b128/hit
//    (was 8); 16 v_dot2_f32_f16 per hit.
//  - Parallel hash lookups: bitmap-passing candidates compacted to LDS, lane j
//    resolves candidate j (removes per-lane serial dependent lookups).
//  - Overflow (cand>96 / hits>48) -> rare fp32 broadcast fallback into accum.

#define ZD 41
#define YD 1024
#define XD 1024

constexpr int CIN = 32;
constexpr int COUT = 64;
constexpr unsigned HASH_BITS = 20;               // 2^20 slots, load ~0.29
constexpr unsigned CAP = 1u << HASH_BITS;
constexpr unsigned GROUP_BITS = HASH_BITS - 3;   // octet groups
constexpr unsigned long long EMPTY = ~0ull;
constexpr unsigned NVOX = ZD * YD * XD;
constexpr unsigned NOCT = NVOX / 8;
constexpr unsigned BMWORDS = (NOCT + 31) / 32;   // 656 KB (bit=1: EMPTY)
constexpr int PPW = 16;                          // points per wave
constexpr int CAND_CAP = 96;                     // candidate slots per wave
constexpr int HROWS = 48;                        // staged hit rows per wave
constexpr int WPACK_N = 27 * 4 * 64;             // uint4 entries

typedef _Float16 half2_t __attribute__((ext_vector_type(2)));
typedef _Float16 half8_t __attribute__((ext_vector_type(8)));
typedef __fp16 pk2_t __attribute__((ext_vector_type(2)));   // cvt_pkrtz result type
typedef float floatx4 __attribute__((ext_vector_type(4)));

union H2U { pk2_t p; half2_t h; unsigned u; };
union H8U { half8_t v; half2_t h2[4]; pk2_t p2[4]; uint4 u4; };

__device__ __forceinline__ unsigned hash_slot(unsigned lin) {
    unsigned gh = ((lin >> 3) * 2654435761u) >> (32 - GROUP_BITS);
    return (gh << 3) | (lin & 7u);
}

__global__ void build_hash_kernel(const int4* __restrict__ idx, int n,
                                  unsigned long long* __restrict__ table,
                                  unsigned* __restrict__ bitmap,
                                  const float* __restrict__ weight,
                                  uint4* __restrict__ wpack) {
    int i = blockIdx.x * blockDim.x + threadIdx.x;
    // --- pack fp32 weights -> f16 pairs: wpack[(k*4+g)*64+co] = 8 f16 (ci 8g..8g+7)
    if (i < WPACK_N) {
        int co = i & 63, g = (i >> 6) & 3, k = i >> 8;
        const float* b = weight + k * (CIN * COUT) + (8 * g) * COUT + co;
        H2U p0, p1, p2, p3;
        p0.p = __builtin_amdgcn_cvt_pkrtz(b[0 * COUT], b[1 * COUT]);
        p1.p = __builtin_amdgcn_cvt_pkrtz(b[2 * COUT], b[3 * COUT]);
        p2.p = __builtin_amdgcn_cvt_pkrtz(b[4 * COUT], b[5 * COUT]);
        p3.p = __builtin_amdgcn_cvt_pkrtz(b[6 * COUT], b[7 * COUT]);
        wpack[i] = make_uint4(p0.u, p1.u, p2.u, p3.u);
    }
    if (i >= n) return;
    int4 c = idx[i];                             // (b, z, y, x)
    unsigned lin = (unsigned)(c.y * (YD * XD) + c.z * XD + c.w);
    unsigned g = lin >> 3;
    atomicAnd(&bitmap[g >> 5], ~(1u << (g & 31u)));   // clear bit = occupied
    unsigned long long packed = ((unsigned long long)(unsigned)i << 32) | (unsigned long long)lin;
    unsigned h = hash_slot(lin);
    while (atomicCAS(&table[h], EMPTY, packed) != EMPTY) {
        h = (h + 1) & (CAP - 1);                 // coords unique -> no dup check
    }
}

__device__ __forceinline__ int lookup(const unsigned long long* __restrict__ table,
                                      unsigned lin) {
    unsigned h = hash_slot(lin);
    while (true) {
        unsigned long long s = table[h];
        if (s == EMPTY) return -1;
        if ((unsigned)s == lin) return (int)(s >> 32);
        h = (h + 1) & (CAP - 1);
    }
}

// fp32 broadcast fallback tap (rare overflow paths) into LDS accum.
__device__ __forceinline__ void fb_tap(const float* __restrict__ feat,
                                       const float* __restrict__ weight,
                                       float* __restrict__ acc,
                                       int ni, int pt, int k, int lane) {
    const float4* fr = (const float4*)(feat + (size_t)ni * CIN);
    const float* wk = weight + k * (CIN * COUT) + lane;
    float s0 = 0.f, s1 = 0.f, s2 = 0.f, s3 = 0.f;
#pragma unroll
    for (int q = 0; q < 8; ++q) {
        float4 f = fr[q];
        s0 = fmaf(f.x, wk[(4 * q + 0) * COUT], s0);
        s1 = fmaf(f.y, wk[(4 * q + 1) * COUT], s1);
        s2 = fmaf(f.z, wk[(4 * q + 2) * COUT], s2);
        s3 = fmaf(f.w, wk[(4 * q + 3) * COUT], s3);
    }
    acc[pt * COUT + lane] += (s0 + s1) + (s2 + s3);
}

__global__ __launch_bounds__(256) void subm_conv_kernel(
    const float* __restrict__ feat, const int4* __restrict__ idx,
    const float* __restrict__ weight, const uint4* __restrict__ wpack,
    const unsigned long long* __restrict__ table,
    const unsigned* __restrict__ bitmap, float* __restrict__ out, int n) {
    __shared__ unsigned rows_l[4][HROWS * 16];          // 12 KB: f16 rows (16 u32 each)
    __shared__ float accum_l[4][PPW * COUT];            // 16 KB
    __shared__ unsigned long long cand_l[4][CAND_CAP];  // 3 KB
    __shared__ unsigned hlist_l[4][HROWS];              // 768 B

    int wid = threadIdx.x >> 6;
    int lane = threadIdx.x & 63;
    int p0 = (blockIdx.x * 4 + wid) * PPW;
    if (p0 >= n) return;
    int np = min(PPW, n - p0);

    // --- coords: 4 lanes per point
    int pt = lane >> 2;
    int4 c = idx[p0 + (pt < np ? pt : 0)];

    // --- bitmap words for 7 probe rounds (independent, issued early)
    unsigned nlin_t[7];
    unsigned bmw[7];
    bool try_t[7];
#pragma unroll
    for (int t = 0; t < 7; ++t) {
        int off = (lane & 3) + 4 * t;
        int k = off + (off >= 13);
        bool ok = (off < 26) && (pt < np);
        int dz = k / 9 - 1, dy = (k / 3) % 3 - 1, dx = k % 3 - 1;
        int nz = c.y + dz, ny = c.z + dy, nx = c.w + dx;
        ok = ok && (unsigned)nz < (unsigned)ZD && (unsigned)ny < (unsigned)YD &&
             (unsigned)nx < (unsigned)XD;
        unsigned nlin = ok ? (unsigned)(nz * (YD * XD) + ny * XD + nx) : 0u;
        nlin_t[t] = nlin;
        try_t[t] = ok;
        bmw[t] = ok ? bitmap[(nlin >> 3) >> 5] : ~0u;   // bit=1 means empty
    }

    // --- center tap via MFMA f16: D[pt][co] = feat[p0+pt][:] @ W13
    int arow = lane & 15, aq = lane >> 4;               // A: m=lane&15, k=aq*8+j
    int rowp = p0 + (arow < np ? arow : np - 1);
    float4 af0 = *(const float4*)(feat + (size_t)rowp * CIN + aq * 8);
    float4 af1 = *(const float4*)(feat + (size_t)rowp * CIN + aq * 8 + 4);
    H8U afrag;
    afrag.p2[0] = __builtin_amdgcn_cvt_pkrtz(af0.x, af0.y);
    afrag.p2[1] = __builtin_amdgcn_cvt_pkrtz(af0.z, af0.w);
    afrag.p2[2] = __builtin_amdgcn_cvt_pkrtz(af1.x, af1.y);
    afrag.p2[3] = __builtin_amdgcn_cvt_pkrtz(af1.z, af1.w);

    floatx4 cacc[4];
#pragma unroll
    for (int ch = 0; ch < 4; ++ch) {
        H8U bfrag;                                       // B: k=aq*8+j, n=lane&15
        bfrag.u4 = wpack[(13 * 4 + aq) * 64 + ch * 16 + (lane & 15)];
        floatx4 z = {0.f, 0.f, 0.f, 0.f};
        cacc[ch] = __builtin_amdgcn_mfma_f32_16x16x32_f16(afrag.v, bfrag.v, z, 0, 0, 0);
    }
    // scatter C into accum: row=(lane>>4)*4+reg, col=ch*16+(lane&15)
#pragma unroll
    for (int ch = 0; ch < 4; ++ch) {
#pragma unroll
        for (int r = 0; r < 4; ++r) {
            accum_l[wid][((lane >> 4) * 4 + r) * COUT + ch * 16 + (lane & 15)] = cacc[ch][r];
        }
    }

    // --- candidate compaction (bitmap-passing probes) into LDS
    int cbase = 0;
    unsigned ovmask = 0;
#pragma unroll
    for (int t = 0; t < 7; ++t) {
        unsigned nlin = nlin_t[t];
        bool candq = try_t[t] && !((bmw[t] >> ((nlin >> 3) & 31u)) & 1u);
        unsigned long long m = __ballot(candq);
        if (candq) {
            int r = cbase + __popcll(m & ((1ull << lane) - 1ull));
            int off = (lane & 3) + 4 * t;
            int k = off + (off >= 13);
            if (r < CAND_CAP) {
                cand_l[wid][r] = ((unsigned long long)(((unsigned)pt << 5) | (unsigned)k) << 32)
                                 | (unsigned long long)nlin;
            } else {
                ovmask |= 1u << t;
            }
        }
        cbase += __popcll(m);
    }
    int ncand = cbase < CAND_CAP ? cbase : CAND_CAP;
    __asm__ __volatile__("s_waitcnt lgkmcnt(0)" ::: "memory");

    // --- parallel lookups: lane j resolves candidate j
    int hitbase = 0;
    int hni[2];
    unsigned hmeta[2];
    bool hov[2] = {false, false};
#pragma unroll
    for (int sub = 0; sub < 2; ++sub) {
        int j = sub * 64 + lane;
        int ni = -1;
        unsigned meta = 0;
        if (j < ncand) {
            unsigned long long e = cand_l[wid][j];
            meta = (unsigned)(e >> 32);
            ni = lookup(table, (unsigned)e);
        }
        unsigned long long m = __ballot(ni >= 0);
        if (ni >= 0) {
            int hr = hitbase + __popcll(m & ((1ull << lane) - 1ull));
            if (hr < HROWS) {
                hlist_l[wid][hr] = ((unsigned)ni << 9) | meta;
            } else {
                hov[sub] = true; hni[sub] = ni; hmeta[sub] = meta;
            }
        }
        hitbase += __popcll(m);
    }
    int hits = hitbase < HROWS ? hitbase : HROWS;
    __asm__ __volatile__("s_waitcnt lgkmcnt(0)" ::: "memory");

    // --- stage all hit rows as f16 (lane e handles row e>>2, seg e&3 = 8 ci)
    for (int e = lane; e < hits * 4; e += 64) {
        int r = e >> 2, s = e & 3;
        int ni = (int)(hlist_l[wid][r] >> 9);
        float4 u = *(const float4*)(feat + (size_t)ni * CIN + s * 8);
        float4 v = *(const float4*)(feat + (size_t)ni * CIN + s * 8 + 4);
        H2U q0, q1, q2, q3;
        q0.p = __builtin_amdgcn_cvt_pkrtz(u.x, u.y);
        q1.p = __builtin_amdgcn_cvt_pkrtz(u.z, u.w);
        q2.p = __builtin_amdgcn_cvt_pkrtz(v.x, v.y);
        q3.p = __builtin_amdgcn_cvt_pkrtz(v.z, v.w);
        *(uint4*)&rows_l[wid][r * 16 + s * 4] = make_uint4(q0.u, q1.u, q2.u, q3.u);
    }
    __asm__ __volatile__("s_waitcnt vmcnt(0) lgkmcnt(0)" ::: "memory");

    // --- hit taps: lane = co; 4x(ds_read_b128 + uint4 weight load + 4 fdot2)
    for (int j = 0; j < hits; ++j) {
        unsigned meta = hlist_l[wid][j] & 511u;
        int k = (int)(meta & 31u);
        int pt2 = (int)(meta >> 5);
        float s = 0.f;
#pragma unroll
        for (int g = 0; g < 4; ++g) {
            H8U fv, wv;
            fv.u4 = *(const uint4*)&rows_l[wid][j * 16 + g * 4];
            wv.u4 = wpack[(k * 4 + g) * 64 + lane];
            s = __builtin_amdgcn_fdot2(fv.h2[0], wv.h2[0], s, false);
            s = __builtin_amdgcn_fdot2(fv.h2[1], wv.h2[1], s, false);
            s = __builtin_amdgcn_fdot2(fv.h2[2], wv.h2[2], s, false);
            s = __builtin_amdgcn_fdot2(fv.h2[3], wv.h2[3], s, false);
        }
        accum_l[wid][pt2 * COUT + lane] += s;
    }

    // --- rare overflow paths (fp32 broadcast fallback)
    if (__builtin_expect(cbase > CAND_CAP, 0)) {
#pragma unroll
        for (int t = 0; t < 7; ++t) {
            unsigned long long m = __ballot((ovmask >> t) & 1u);
            while (m) {
                int src = __ffsll((unsigned long long)m) - 1;
                m &= m - 1;
                unsigned nlin = __shfl(nlin_t[t], src);
                int pt2 = src >> 2;
                int off = (src & 3) + 4 * t;
                int k = off + (off >= 13);
                int ni = lookup(table, nlin);
                if (ni >= 0) fb_tap(feat, weight, accum_l[wid], ni, pt2, k, lane);
            }
        }
    }
    if (__builtin_expect(hitbase > HROWS, 0)) {
#pragma unroll
        for (int sub = 0; sub < 2; ++sub) {
            unsigned long long m = __ballot(hov[sub]);
            while (m) {
                int src = __ffsll((unsigned long long)m) - 1;
                m &= m - 1;
                int ni = __shfl(hni[sub], src);
                unsigned meta = (unsigned)__shfl((int)hmeta[sub], src);
                fb_tap(feat, weight, accum_l[wid], ni, (int)((meta >> 5) & 15u),
                       (int)(meta & 31u), lane);
            }
        }
    }
    __asm__ __volatile__("s_waitcnt lgkmcnt(0)" ::: "memory");

    // --- coalesced store pass
    for (int g = 0; g < np; ++g) {
        __builtin_nontemporal_store(accum_l[wid][g * COUT + lane],
                                    &out[(size_t)(p0 + g) * COUT + lane]);
    }
}

extern "C" void kernel_launch(void* const* d_in, const int* in_sizes, int n_in,
                              void* d_out, int out_size, void* d_ws, size_t ws_size,
                              hipStream_t stream) {
    const float* feat   = (const float*)d_in[0];   // [N, 32]
    const int4*  idx    = (const int4*)d_in[1];    // [N, 4] int32 (b,z,y,x)
    const float* weight = (const float*)d_in[2];   // [27, 32, 64]
    float* out = (float*)d_out;                    // [N, 64]
    int n = in_sizes[0] / CIN;

    unsigned char* base = (unsigned char*)d_ws;
    unsigned long long* table = (unsigned long long*)base;              // 8 MB
    unsigned* bitmap = (unsigned*)(base + (size_t)CAP * 8);             // 656 KB
    uint4* wpack = (uint4*)(base + (size_t)CAP * 8 + (size_t)BMWORDS * 4);  // 108 KB

    // One memset covers table (0xFF = EMPTY) and bitmap (0xFF = all-empty).
    hipMemsetAsync(table, 0xFF, (size_t)CAP * 8 + (size_t)BMWORDS * 4, stream);

    int bwork = n > WPACK_N ? n : WPACK_N;
    int bblocks = (bwork + 255) / 256;
    build_hash_kernel<<<bblocks, 256, 0, stream>>>(idx, n, table, bitmap, weight, wpack);

    int ppb = 4 * PPW;                             // 64 points per block
    int cblocks = (n + ppb - 1) / ppb;
    subm_conv_kernel<<<cblocks, 256, 0, stream>>>(feat, idx, weight, wpack, table,
                                                  bitmap, out, n);
}